// Round 2
// baseline (556.768 us; speedup 1.0000x reference)
//
#include <hip/hip_runtime.h>

#define N_TOK 2048
#define V_DIM 204
#define H_DIM 160
#define G_DIM 320
#define BM 128
#define LN_EPSF 1e-5f

typedef short s8v __attribute__((ext_vector_type(8)));
typedef unsigned short u16x8 __attribute__((ext_vector_type(8)));
typedef float f32x4 __attribute__((ext_vector_type(4)));

// per-v bf16 weight image, K-major: [W1T][GLU half0][GLU half1]
// each sub-image: [chunk=k/8][row=out_col][8 bf16] = 20*160*16 B
#define IMG_SUB 51200
#define IMG_PER_V (3 * IMG_SUB)

typedef unsigned int __attribute__((address_space(1))) as1_u32;
typedef unsigned int __attribute__((address_space(3))) as3_u32;

__device__ __forceinline__ void gl_lds16(const void* g, void* l) {
    // async global->LDS, 16B per lane; LDS dest = wave-uniform base + lane*16
    __builtin_amdgcn_global_load_lds((as1_u32*)g, (as3_u32*)l, 16, 0, 0);
}

__device__ __forceinline__ unsigned short f2bf(float f) {
    union { float f; unsigned int u; } a;
    a.f = f;
    unsigned int r = a.u + 0x7fffu + ((a.u >> 16) & 1u);  // RNE
    return (unsigned short)(r >> 16);
}

__global__ __launch_bounds__(256) void prep_weights(const float* __restrict__ fc2_w,
                                                    const float* __restrict__ glu_w,
                                                    unsigned short* __restrict__ ws) {
    int v = blockIdx.x;
    int t = threadIdx.x;
    __shared__ float tile[H_DIM][H_DIM + 1];
    const float* w1 = fc2_w + (size_t)v * H_DIM * H_DIM;
    for (int i = t; i < H_DIM * H_DIM; i += 256)
        tile[i / H_DIM][i % H_DIM] = w1[i];
    __syncthreads();
    char* img = (char*)ws + (size_t)v * IMG_PER_V;
    // W1T sub-image: unit index = chunk*160 + kout; content = fc2_w[chunk*8+j][kout]
    for (int c = t; c < 3200; c += 256) {
        int chunk = c / 160, kout = c % 160;
        u16x8 pk;
        #pragma unroll
        for (int j = 0; j < 8; j++) pk[j] = f2bf(tile[chunk * 8 + j][kout]);
        *(u16x8*)(img + (size_t)c * 16) = pk;
    }
    // GLU halves: already NT ([g][h]); unit = half_base + chunk*160 + grow
    const float* w2 = glu_w + (size_t)v * G_DIM * H_DIM;
    for (int c = t; c < 6400; c += 256) {
        int chunk = c % 20, grow = (c / 20) % 160, half = c / 3200;
        const float* src = w2 + (size_t)(half * H_DIM + grow) * H_DIM + chunk * 8;
        f32x4 lo = *(const f32x4*)src;
        f32x4 hi = *(const f32x4*)(src + 4);
        u16x8 pk;
        #pragma unroll
        for (int j = 0; j < 4; j++) { pk[j] = f2bf(lo[j]); pk[4 + j] = f2bf(hi[j]); }
        *(u16x8*)(img + IMG_SUB + (size_t)half * IMG_SUB + (size_t)(chunk * 160 + grow) * 16) = pk;
    }
}

__global__ __launch_bounds__(512, 2) void grn_main(
    const float* __restrict__ x,
    const float* __restrict__ fc1_w, const float* __restrict__ fc1_b,
    const float* __restrict__ fc2_b, const float* __restrict__ glu_b,
    const float* __restrict__ skip_w, const float* __restrict__ skip_b,
    const float* __restrict__ ln_g, const float* __restrict__ ln_b,
    const unsigned short* __restrict__ ws, float* __restrict__ out)
{
    // K-major LDS: [chunk][row][16B]
    __shared__ __align__(16) unsigned short h_lds[20 * 128 * 8];   // 40960 B
    __shared__ __align__(16) unsigned short w_lds[20 * 160 * 8];   // 51200 B
    __shared__ __align__(16) unsigned short c1_lds[20 * 128 * 8];  // 40960 B

    int bid = blockIdx.x;
    // XCD-bijective swizzle: 3264 blocks = 8 XCDs * 408; all 16 tiles of a v on one XCD
    int swb = (bid & 7) * 408 + (bid >> 3);
    int v  = swb >> 4;
    int n0 = (swb & 15) * BM;

    int t = threadIdx.x;
    int lane = t & 63;
    int wv = t >> 6;
    int wr = wv >> 1;      // row group 0..3 -> rows wr*32..+32
    int wc = wv & 1;       // col group 0..1 -> cols wc*80..+80
    int col = lane & 15;
    int kg  = lane >> 4;

    const char* img = (const char*)ws + (size_t)v * IMG_PER_V;

    // ---- stage W1T via async global->LDS (linear, K-major) ----
    for (int i = t; i < 3200; i += 512)
        gl_lds16(img + (size_t)i * 16, (char*)w_lds + i * 16);

    // ---- produce h = elu(x*fc1_w + fc1_b), K-major bf16 ----
    const float* fw = fc1_w + v * H_DIM;
    const float* fb = fc1_b + v * H_DIM;
    for (int i = t; i < 2560; i += 512) {
        int chunk = i >> 7, row = i & 127;
        float xv = x[(size_t)(n0 + row) * V_DIM + v];
        int k0 = chunk * 8;
        u16x8 pk;
        #pragma unroll
        for (int j = 0; j < 8; j++) {
            float z = xv * fw[k0 + j] + fb[k0 + j];
            float e = z > 0.f ? z : (__expf(z) - 1.f);
            pk[j] = f2bf(e);
        }
        *(u16x8*)((char*)h_lds + chunk * 2048 + row * 16) = pk;
    }
    __syncthreads();  // bar1: h visible, W1T staged (vmcnt drained)

    // ---- GEMM1: c1 = h @ fc2_w ----
    s8v a1[2][5];
    #pragma unroll
    for (int m = 0; m < 2; m++)
        #pragma unroll
        for (int kk = 0; kk < 5; kk++)
            a1[m][kk] = *(const s8v*)((const char*)h_lds +
                         (kk * 4 + kg) * 2048 + (wr * 32 + m * 16 + col) * 16);

    f32x4 acc[2][5];
    #pragma unroll
    for (int m = 0; m < 2; m++)
        #pragma unroll
        for (int n = 0; n < 5; n++) acc[m][n] = (f32x4){0.f, 0.f, 0.f, 0.f};

    #pragma unroll
    for (int kk = 0; kk < 5; kk++) {
        s8v b[5];
        #pragma unroll
        for (int n = 0; n < 5; n++)
            b[n] = *(const s8v*)((const char*)w_lds +
                    (kk * 4 + kg) * 2560 + (wc * 80 + n * 16 + col) * 16);
        #pragma unroll
        for (int n = 0; n < 5; n++)
            #pragma unroll
            for (int m = 0; m < 2; m++)
                acc[m][n] = __builtin_amdgcn_mfma_f32_16x16x32_bf16(a1[m][kk], b[n], acc[m][n], 0, 0, 0);
    }
    __syncthreads();  // bar2: all w_lds reads done

    // ---- stage GLU half0; overlap with epilogue1 (c1 -> LDS, K-major bf16) ----
    for (int i = t; i < 3200; i += 512)
        gl_lds16(img + IMG_SUB + (size_t)i * 16, (char*)w_lds + i * 16);

    const float* f2b = fc2_b + v * H_DIM;
    #pragma unroll
    for (int n = 0; n < 5; n++) {
        int gc = wc * 80 + n * 16 + col;
        float bias = f2b[gc];
        int cbase = (gc >> 3) * 2048 + (gc & 7) * 2;
        #pragma unroll
        for (int m = 0; m < 2; m++)
            #pragma unroll
            for (int j = 0; j < 4; j++) {
                int row = wr * 32 + m * 16 + kg * 4 + j;
                *(unsigned short*)((char*)c1_lds + cbase + row * 16) = f2bf(acc[m][n][j] + bias);
            }
    }
    __syncthreads();  // bar3: c1 visible, half0 staged

    // ---- GEMM2a: fc_out ----
    s8v a2[2][5];
    #pragma unroll
    for (int m = 0; m < 2; m++)
        #pragma unroll
        for (int kk = 0; kk < 5; kk++)
            a2[m][kk] = *(const s8v*)((const char*)c1_lds +
                         (kk * 4 + kg) * 2048 + (wr * 32 + m * 16 + col) * 16);

    f32x4 af[2][5];
    #pragma unroll
    for (int m = 0; m < 2; m++)
        #pragma unroll
        for (int n = 0; n < 5; n++) af[m][n] = (f32x4){0.f, 0.f, 0.f, 0.f};

    #pragma unroll
    for (int kk = 0; kk < 5; kk++) {
        s8v b[5];
        #pragma unroll
        for (int n = 0; n < 5; n++)
            b[n] = *(const s8v*)((const char*)w_lds +
                    (kk * 4 + kg) * 2560 + (wc * 80 + n * 16 + col) * 16);
        #pragma unroll
        for (int n = 0; n < 5; n++)
            #pragma unroll
            for (int m = 0; m < 2; m++)
                af[m][n] = __builtin_amdgcn_mfma_f32_16x16x32_bf16(a2[m][kk], b[n], af[m][n], 0, 0, 0);
    }
    __syncthreads();  // bar4: half0 reads done

    // ---- stage GLU half1 ----
    for (int i = t; i < 3200; i += 512)
        gl_lds16(img + 2 * IMG_SUB + (size_t)i * 16, (char*)w_lds + i * 16);
    __syncthreads();  // bar5: half1 staged

    // ---- GEMM2b: gate ----
    f32x4 ag[2][5];
    #pragma unroll
    for (int m = 0; m < 2; m++)
        #pragma unroll
        for (int n = 0; n < 5; n++) ag[m][n] = (f32x4){0.f, 0.f, 0.f, 0.f};

    #pragma unroll
    for (int kk = 0; kk < 5; kk++) {
        s8v b[5];
        #pragma unroll
        for (int n = 0; n < 5; n++)
            b[n] = *(const s8v*)((const char*)w_lds +
                    (kk * 4 + kg) * 2560 + (wc * 80 + n * 16 + col) * 16);
        #pragma unroll
        for (int n = 0; n < 5; n++)
            #pragma unroll
            for (int m = 0; m < 2; m++)
                ag[m][n] = __builtin_amdgcn_mfma_f32_16x16x32_bf16(a2[m][kk], b[n], ag[m][n], 0, 0, 0);
    }

    // ---- epilogue2: GLU + skip + LayerNorm (cross-wave) + store ----
    const float* gb  = glu_b + v * G_DIM;
    const float* sw_ = skip_w + v * H_DIM;
    const float* sb_ = skip_b + v * H_DIM;

    float xr[2][4];
    #pragma unroll
    for (int m = 0; m < 2; m++)
        #pragma unroll
        for (int j = 0; j < 4; j++)
            xr[m][j] = x[(size_t)(n0 + wr * 32 + m * 16 + kg * 4 + j) * V_DIM + v];

    float y[2][5][4];
    float sum[2][4] = {}, ssq[2][4] = {};
    #pragma unroll
    for (int n = 0; n < 5; n++) {
        int gc = wc * 80 + n * 16 + col;
        float bfo = gb[gc], bga = gb[H_DIM + gc];
        float sww = sw_[gc], sbb = sb_[gc];
        #pragma unroll
        for (int m = 0; m < 2; m++)
            #pragma unroll
            for (int j = 0; j < 4; j++) {
                float fo = af[m][n][j] + bfo;
                float ga = ag[m][n][j] + bga;
                float hh = fo / (1.f + __expf(-ga));
                float yv = xr[m][j] * sww + sbb + hh;
                y[m][n][j] = yv;
                sum[m][j] += yv;
                ssq[m][j] += yv * yv;
            }
    }
    #pragma unroll
    for (int msk = 1; msk < 16; msk <<= 1)
        #pragma unroll
        for (int m = 0; m < 2; m++)
            #pragma unroll
            for (int j = 0; j < 4; j++) {
                sum[m][j] += __shfl_xor(sum[m][j], msk, 64);
                ssq[m][j] += __shfl_xor(ssq[m][j], msk, 64);
            }

    // cross-wave (wc pair) reduction through LDS scratch overlaid on dead h_lds
    float2* red = (float2*)h_lds;  // red[row*2 + wc]
    if (col == 0) {
        #pragma unroll
        for (int m = 0; m < 2; m++)
            #pragma unroll
            for (int j = 0; j < 4; j++) {
                int row = wr * 32 + m * 16 + kg * 4 + j;
                red[row * 2 + wc] = make_float2(sum[m][j], ssq[m][j]);
            }
    }
    __syncthreads();  // bar6

    float mu_[2][4], rs_[2][4];
    #pragma unroll
    for (int m = 0; m < 2; m++)
        #pragma unroll
        for (int j = 0; j < 4; j++) {
            int row = wr * 32 + m * 16 + kg * 4 + j;
            f32x4 p = *(const f32x4*)&red[row * 2];
            float mu = (p[0] + p[2]) * (1.f / H_DIM);
            float var = (p[1] + p[3]) * (1.f / H_DIM) - mu * mu;
            mu_[m][j] = mu;
            rs_[m][j] = rsqrtf(var + LN_EPSF);
        }

    #pragma unroll
    for (int n = 0; n < 5; n++) {
        int gc = wc * 80 + n * 16 + col;
        float g = ln_g[gc], be = ln_b[gc];
        #pragma unroll
        for (int m = 0; m < 2; m++)
            #pragma unroll
            for (int j = 0; j < 4; j++) {
                int row = n0 + wr * 32 + m * 16 + kg * 4 + j;
                float val = (y[m][n][j] - mu_[m][j]) * rs_[m][j] * g + be;
                __builtin_nontemporal_store(val, &out[((size_t)row * V_DIM + v) * H_DIM + gc]);
            }
    }
}

// correctness fallback if ws is too small for the bf16 weight images
__global__ __launch_bounds__(160) void grn_fallback(
    const float* __restrict__ x,
    const float* __restrict__ fc1_w, const float* __restrict__ fc1_b,
    const float* __restrict__ fc2_w, const float* __restrict__ fc2_b,
    const float* __restrict__ glu_w, const float* __restrict__ glu_b,
    const float* __restrict__ skip_w, const float* __restrict__ skip_b,
    const float* __restrict__ ln_g, const float* __restrict__ ln_b,
    float* __restrict__ out)
{
    int n = blockIdx.x / V_DIM, v = blockIdx.x % V_DIM;
    int k = threadIdx.x;
    __shared__ float hb[H_DIM], c1[H_DIM], yb[H_DIM];
    float xv = x[(size_t)n * V_DIM + v];
    float z = xv * fc1_w[v * H_DIM + k] + fc1_b[v * H_DIM + k];
    hb[k] = z > 0.f ? z : (__expf(z) - 1.f);
    __syncthreads();
    const float* w1 = fc2_w + (size_t)v * H_DIM * H_DIM;
    float s = fc2_b[v * H_DIM + k];
    for (int i = 0; i < H_DIM; i++) s += hb[i] * w1[(size_t)i * H_DIM + k];
    c1[k] = s;
    __syncthreads();
    const float* w2 = glu_w + (size_t)v * G_DIM * H_DIM;
    float sf = glu_b[v * G_DIM + k], sg = glu_b[v * G_DIM + H_DIM + k];
    for (int i = 0; i < H_DIM; i++) {
        float cv = c1[i];
        sf += cv * w2[(size_t)k * H_DIM + i];
        sg += cv * w2[(size_t)(k + H_DIM) * H_DIM + i];
    }
    float y = xv * skip_w[v * H_DIM + k] + skip_b[v * H_DIM + k] + sf / (1.f + __expf(-sg));
    yb[k] = y;
    __syncthreads();
    float sum = 0.f, ssq = 0.f;
    for (int i = 0; i < H_DIM; i++) { sum += yb[i]; ssq += yb[i] * yb[i]; }
    float mu = sum / H_DIM;
    float var = ssq / H_DIM - mu * mu;
    out[((size_t)n * V_DIM + v) * H_DIM + k] =
        (y - mu) * rsqrtf(var + LN_EPSF) * ln_g[k] + ln_b[k];
}

extern "C" void kernel_launch(void* const* d_in, const int* in_sizes, int n_in,
                              void* d_out, int out_size, void* d_ws, size_t ws_size,
                              hipStream_t stream) {
    const float* x      = (const float*)d_in[0];
    const float* fc1_w  = (const float*)d_in[1];
    const float* fc1_b  = (const float*)d_in[2];
    const float* fc2_w  = (const float*)d_in[3];
    const float* fc2_b  = (const float*)d_in[4];
    const float* glu_w  = (const float*)d_in[5];
    const float* glu_b  = (const float*)d_in[6];
    const float* skip_w = (const float*)d_in[7];
    const float* skip_b = (const float*)d_in[8];
    const float* ln_g   = (const float*)d_in[9];
    const float* ln_b   = (const float*)d_in[10];
    float* out = (float*)d_out;

    size_t need = (size_t)V_DIM * IMG_PER_V;  // 31,334,400 B
    if (ws_size >= need) {
        unsigned short* ws = (unsigned short*)d_ws;
        prep_weights<<<V_DIM, 256, 0, stream>>>(fc2_w, glu_w, ws);
        grn_main<<<V_DIM * (N_TOK / BM), 512, 0, stream>>>(
            x, fc1_w, fc1_b, fc2_b, glu_b, skip_w, skip_b, ln_g, ln_b, ws, out);
    } else {
        grn_fallback<<<N_TOK * V_DIM, 160, 0, stream>>>(
            x, fc1_w, fc1_b, fc2_w, fc2_b, glu_w, glu_b, skip_w, skip_b, ln_g, ln_b, out);
    }
}

// Round 6
// 541.948 us; speedup vs baseline: 1.0273x; 1.0273x over previous
//
#include <hip/hip_runtime.h>

#define N_TOK 2048
#define V_DIM 204
#define H_DIM 160
#define G_DIM 320
#define BM 64
#define LN_EPSF 1e-5f

typedef short s8v __attribute__((ext_vector_type(8)));
typedef unsigned short u16x8 __attribute__((ext_vector_type(8)));
typedef float f32x4 __attribute__((ext_vector_type(4)));

// per-v bf16 weight image, K-major: [W1T][GLU half0][GLU half1]
// each sub-image: [chunk=k/8][row=out_col][8 bf16] = 20*160*16 B
#define IMG_SUB 51200
#define IMG_PER_V (3 * IMG_SUB)

typedef unsigned int __attribute__((address_space(1))) as1_u32;
typedef unsigned int __attribute__((address_space(3))) as3_u32;

__device__ __forceinline__ void gl_lds16(const void* g, void* l) {
    __builtin_amdgcn_global_load_lds((as1_u32*)g, (as3_u32*)l, 16, 0, 0);
}

__device__ __forceinline__ unsigned short f2bf(float f) {
    union { float f; unsigned int u; } a;
    a.f = f;
    unsigned int r = a.u + 0x7fffu + ((a.u >> 16) & 1u);  // RNE
    return (unsigned short)(r >> 16);
}

// prep: 4 blocks per v. p=0,1: fc2 transpose (kout half p). p=2,3: glu half (p-2).
__global__ __launch_bounds__(256) void prep_weights(const float* __restrict__ fc2_w,
                                                    const float* __restrict__ glu_w,
                                                    unsigned short* __restrict__ ws) {
    int b = blockIdx.x;
    int v = b >> 2, p = b & 3;
    int t = threadIdx.x;
    char* img = (char*)ws + (size_t)v * IMG_PER_V;
    if (p < 2) {
        // fc2_w transpose for kout in [p*80, p*80+80)
        __shared__ float tile[H_DIM][81];
        const float* w1 = fc2_w + (size_t)v * H_DIM * H_DIM + p * 80;
        for (int i = t; i < H_DIM * 80; i += 256) {
            int r = i / 80, c = i % 80;
            tile[r][c] = w1[(size_t)r * H_DIM + c];
        }
        __syncthreads();
        for (int c2 = t; c2 < 20 * 80; c2 += 256) {
            int chunk = c2 / 80, ko = c2 % 80;
            u16x8 pk;
            #pragma unroll
            for (int j = 0; j < 8; j++) pk[j] = f2bf(tile[chunk * 8 + j][ko]);
            *(u16x8*)(img + (size_t)(chunk * 160 + p * 80 + ko) * 16) = pk;
        }
    } else {
        // glu half: rows [half*160, +160) of glu_w; no transpose, granule repack
        int half = p - 2;
        const float* w2 = glu_w + (size_t)v * G_DIM * H_DIM + (size_t)half * H_DIM * H_DIM;
        char* dst = img + IMG_SUB + (size_t)half * IMG_SUB;
        for (int c = t; c < 3200; c += 256) {
            int grow = c / 20, chunk = c % 20;   // read-coalesced order
            const float* src = w2 + (size_t)grow * H_DIM + chunk * 8;
            f32x4 lo = *(const f32x4*)src;
            f32x4 hi = *(const f32x4*)(src + 4);
            u16x8 pk;
            #pragma unroll
            for (int j = 0; j < 4; j++) { pk[j] = f2bf(lo[j]); pk[4 + j] = f2bf(hi[j]); }
            *(u16x8*)(dst + (size_t)(chunk * 160 + grow) * 16) = pk;
        }
    }
}

__global__ __launch_bounds__(256, 2) void grn_main(
    const float* __restrict__ x,
    const float* __restrict__ fc1_w, const float* __restrict__ fc1_b,
    const float* __restrict__ fc2_b, const float* __restrict__ glu_b,
    const float* __restrict__ skip_w, const float* __restrict__ skip_b,
    const float* __restrict__ ln_g, const float* __restrict__ ln_b,
    const unsigned short* __restrict__ ws, float* __restrict__ out)
{
    // K-major LDS: [chunk][row][16B]; hc holds h, then c1 (overlay), then LN scratch
    __shared__ __align__(16) unsigned short w_lds[20 * 160 * 8];  // 51200 B
    __shared__ __align__(16) unsigned short hc_lds[20 * 64 * 8];  // 20480 B

    int bid = blockIdx.x;
    // XCD-bijective swizzle: 6528 blocks = 8 XCDs * 816; 32 tiles of a v adjacent on one XCD
    int swb = (bid & 7) * 816 + (bid >> 3);
    int v  = swb >> 5;
    int n0 = (swb & 31) * BM;

    int t = threadIdx.x;
    int lane = t & 63;
    int wv = t >> 6;
    int wr = wv >> 1;      // rows wr*32..+32
    int wc = wv & 1;       // cols wc*80..+80
    int col = lane & 15;
    int kg  = lane >> 4;

    const char* img = (const char*)ws + (size_t)v * IMG_PER_V;

    // ---- stage W1T (async, linear K-major) ----
    for (int i = t; i < 3200; i += 256)
        gl_lds16(img + (size_t)i * 16, (char*)w_lds + i * 16);

    // ---- produce h = elu(x*fc1_w + fc1_b), K-major bf16 ----
    const float* fw = fc1_w + v * H_DIM;
    const float* fb = fc1_b + v * H_DIM;
    for (int i = t; i < 20 * BM; i += 256) {
        int chunk = i >> 6, row = i & 63;
        float xv = x[(size_t)(n0 + row) * V_DIM + v];
        int k0 = chunk * 8;
        u16x8 pk;
        #pragma unroll
        for (int j = 0; j < 8; j++) {
            float z = xv * fw[k0 + j] + fb[k0 + j];
            float e = z > 0.f ? z : (__expf(z) - 1.f);
            pk[j] = f2bf(e);
        }
        *(u16x8*)((char*)hc_lds + chunk * 1024 + row * 16) = pk;
    }
    __syncthreads();  // bar1: h visible, W1T staged

    int arow = wr * 32 + col;

    // ---- GEMM1: c1 = h @ fc2_w ----
    s8v a1[2][5];
    #pragma unroll
    for (int m = 0; m < 2; m++)
        #pragma unroll
        for (int kk = 0; kk < 5; kk++)
            a1[m][kk] = *(const s8v*)((const char*)hc_lds +
                         (kk * 4 + kg) * 1024 + (arow + m * 16) * 16);

    f32x4 acc[2][5];
    #pragma unroll
    for (int m = 0; m < 2; m++)
        #pragma unroll
        for (int n = 0; n < 5; n++) acc[m][n] = (f32x4){0.f, 0.f, 0.f, 0.f};

    #pragma unroll
    for (int kk = 0; kk < 5; kk++) {
        s8v b[5];
        #pragma unroll
        for (int n = 0; n < 5; n++)
            b[n] = *(const s8v*)((const char*)w_lds +
                    (kk * 4 + kg) * 2560 + (wc * 80 + n * 16 + col) * 16);
        #pragma unroll
        for (int n = 0; n < 5; n++)
            #pragma unroll
            for (int m = 0; m < 2; m++)
                acc[m][n] = __builtin_amdgcn_mfma_f32_16x16x32_bf16(a1[m][kk], b[n], acc[m][n], 0, 0, 0);
    }
    __syncthreads();  // bar2: h reads + W1T reads done

    // ---- stage GLU half0 (overlaps epilogue1) ----
    for (int i = t; i < 3200; i += 256)
        gl_lds16(img + IMG_SUB + (size_t)i * 16, (char*)w_lds + i * 16);

    // epilogue1: + fc2_b, bf16, into hc (h is dead)
    const float* f2b = fc2_b + v * H_DIM;
    #pragma unroll
    for (int n = 0; n < 5; n++) {
        int gc = wc * 80 + n * 16 + col;
        float bias = f2b[gc];
        int cbase = (gc >> 3) * 1024 + (gc & 7) * 2;
        #pragma unroll
        for (int m = 0; m < 2; m++)
            #pragma unroll
            for (int j = 0; j < 4; j++) {
                int row = wr * 32 + m * 16 + kg * 4 + j;
                *(unsigned short*)((char*)hc_lds + cbase + row * 16) = f2bf(acc[m][n][j] + bias);
            }
    }
    __syncthreads();  // bar3: c1 visible, half0 staged

    // ---- GEMM2a: fc_out ----
    s8v a2[2][5];
    #pragma unroll
    for (int m = 0; m < 2; m++)
        #pragma unroll
        for (int kk = 0; kk < 5; kk++)
            a2[m][kk] = *(const s8v*)((const char*)hc_lds +
                         (kk * 4 + kg) * 1024 + (arow + m * 16) * 16);

    f32x4 af[2][5];
    #pragma unroll
    for (int m = 0; m < 2; m++)
        #pragma unroll
        for (int n = 0; n < 5; n++) af[m][n] = (f32x4){0.f, 0.f, 0.f, 0.f};

    #pragma unroll
    for (int kk = 0; kk < 5; kk++) {
        s8v b[5];
        #pragma unroll
        for (int n = 0; n < 5; n++)
            b[n] = *(const s8v*)((const char*)w_lds +
                    (kk * 4 + kg) * 2560 + (wc * 80 + n * 16 + col) * 16);
        #pragma unroll
        for (int n = 0; n < 5; n++)
            #pragma unroll
            for (int m = 0; m < 2; m++)
                af[m][n] = __builtin_amdgcn_mfma_f32_16x16x32_bf16(a2[m][kk], b[n], af[m][n], 0, 0, 0);
    }
    __syncthreads();  // bar4: half0 reads + c1 reads done

    // ---- stage GLU half1; prefetch epilogue coefficients meanwhile ----
    for (int i = t; i < 3200; i += 256)
        gl_lds16(img + 2 * IMG_SUB + (size_t)i * 16, (char*)w_lds + i * 16);

    const float* gb  = glu_b + v * G_DIM;
    const float* sw_ = skip_w + v * H_DIM;
    const float* sb_ = skip_b + v * H_DIM;
    float bfo[5], bga[5], sww[5], sbb[5], lng[5], lnb[5];
    #pragma unroll
    for (int n = 0; n < 5; n++) {
        int gc = wc * 80 + n * 16 + col;
        bfo[n] = gb[gc]; bga[n] = gb[H_DIM + gc];
        sww[n] = sw_[gc]; sbb[n] = sb_[gc];
        lng[n] = ln_g[gc]; lnb[n] = ln_b[gc];
    }
    float xrow[2][4];
    #pragma unroll
    for (int m = 0; m < 2; m++)
        #pragma unroll
        for (int j = 0; j < 4; j++)
            xrow[m][j] = x[(size_t)(n0 + wr * 32 + m * 16 + kg * 4 + j) * V_DIM + v];
    __syncthreads();  // bar5: half1 staged

    // ---- GEMM2b: gate ----
    f32x4 ag[2][5];
    #pragma unroll
    for (int m = 0; m < 2; m++)
        #pragma unroll
        for (int n = 0; n < 5; n++) ag[m][n] = (f32x4){0.f, 0.f, 0.f, 0.f};

    #pragma unroll
    for (int kk = 0; kk < 5; kk++) {
        s8v b[5];
        #pragma unroll
        for (int n = 0; n < 5; n++)
            b[n] = *(const s8v*)((const char*)w_lds +
                    (kk * 4 + kg) * 2560 + (wc * 80 + n * 16 + col) * 16);
        #pragma unroll
        for (int n = 0; n < 5; n++)
            #pragma unroll
            for (int m = 0; m < 2; m++)
                ag[m][n] = __builtin_amdgcn_mfma_f32_16x16x32_bf16(a2[m][kk], b[n], ag[m][n], 0, 0, 0);
    }

    // ---- epilogue2: GLU + skip + LayerNorm + store ----
    float y[2][5][4];
    float sum[2][4] = {}, ssq[2][4] = {};
    #pragma unroll
    for (int n = 0; n < 5; n++) {
        #pragma unroll
        for (int m = 0; m < 2; m++)
            #pragma unroll
            for (int j = 0; j < 4; j++) {
                float fo = af[m][n][j] + bfo[n];
                float ga = ag[m][n][j] + bga[n];
                float hh = fo / (1.f + __expf(-ga));
                float yv = xrow[m][j] * sww[n] + sbb[n] + hh;
                y[m][n][j] = yv;
                sum[m][j] += yv;
                ssq[m][j] += yv * yv;
            }
    }
    #pragma unroll
    for (int msk = 1; msk < 16; msk <<= 1)
        #pragma unroll
        for (int m = 0; m < 2; m++)
            #pragma unroll
            for (int j = 0; j < 4; j++) {
                sum[m][j] += __shfl_xor(sum[m][j], msk, 64);
                ssq[m][j] += __shfl_xor(ssq[m][j], msk, 64);
            }

    // cross-wave (wc pair) reduction; hc is dead after bar4
    float2* red = (float2*)hc_lds;  // red[row*2 + wc], rows < 64
    if (col == 0) {
        #pragma unroll
        for (int m = 0; m < 2; m++)
            #pragma unroll
            for (int j = 0; j < 4; j++) {
                int row = wr * 32 + m * 16 + kg * 4 + j;
                red[row * 2 + wc] = make_float2(sum[m][j], ssq[m][j]);
            }
    }
    __syncthreads();  // bar6

    float mu_[2][4], rs_[2][4];
    #pragma unroll
    for (int m = 0; m < 2; m++)
        #pragma unroll
        for (int j = 0; j < 4; j++) {
            int row = wr * 32 + m * 16 + kg * 4 + j;
            f32x4 p = *(const f32x4*)&red[row * 2];
            float mu = (p[0] + p[2]) * (1.f / H_DIM);
            float var = (p[1] + p[3]) * (1.f / H_DIM) - mu * mu;
            mu_[m][j] = mu;
            rs_[m][j] = rsqrtf(var + LN_EPSF);
        }

    #pragma unroll
    for (int n = 0; n < 5; n++) {
        int gc = wc * 80 + n * 16 + col;
        #pragma unroll
        for (int m = 0; m < 2; m++)
            #pragma unroll
            for (int j = 0; j < 4; j++) {
                int row = n0 + wr * 32 + m * 16 + kg * 4 + j;
                out[((size_t)row * V_DIM + v) * H_DIM + gc] =
                    (y[m][n][j] - mu_[m][j]) * rs_[m][j] * lng[n] + lnb[n];
            }
    }
}

// correctness fallback if ws is too small for the bf16 weight images
__global__ __launch_bounds__(160) void grn_fallback(
    const float* __restrict__ x,
    const float* __restrict__ fc1_w, const float* __restrict__ fc1_b,
    const float* __restrict__ fc2_w, const float* __restrict__ fc2_b,
    const float* __restrict__ glu_w, const float* __restrict__ glu_b,
    const float* __restrict__ skip_w, const float* __restrict__ skip_b,
    const float* __restrict__ ln_g, const float* __restrict__ ln_b,
    float* __restrict__ out)
{
    int n = blockIdx.x / V_DIM, v = blockIdx.x % V_DIM;
    int k = threadIdx.x;
    __shared__ float hb[H_DIM], c1[H_DIM], yb[H_DIM];
    float xv = x[(size_t)n * V_DIM + v];
    float z = xv * fc1_w[v * H_DIM + k] + fc1_b[v * H_DIM + k];
    hb[k] = z > 0.f ? z : (__expf(z) - 1.f);
    __syncthreads();
    const float* w1 = fc2_w + (size_t)v * H_DIM * H_DIM;
    float s = fc2_b[v * H_DIM + k];
    for (int i = 0; i < H_DIM; i++) s += hb[i] * w1[(size_t)i * H_DIM + k];
    c1[k] = s;
    __syncthreads();
    const float* w2 = glu_w + (size_t)v * G_DIM * H_DIM;
    float sf = glu_b[v * G_DIM + k], sg = glu_b[v * G_DIM + H_DIM + k];
    for (int i = 0; i < H_DIM; i++) {
        float cv = c1[i];
        sf += cv * w2[(size_t)k * H_DIM + i];
        sg += cv * w2[(size_t)(k + H_DIM) * H_DIM + i];
    }
    float y = xv * skip_w[v * H_DIM + k] + skip_b[v * H_DIM + k] + sf / (1.f + __expf(-sg));
    yb[k] = y;
    __syncthreads();
    float sum = 0.f, ssq = 0.f;
    for (int i = 0; i < H_DIM; i++) { sum += yb[i]; ssq += yb[i] * yb[i]; }
    float mu = sum / H_DIM;
    float var = ssq / H_DIM - mu * mu;
    out[((size_t)n * V_DIM + v) * H_DIM + k] =
        (y - mu) * rsqrtf(var + LN_EPSF) * ln_g[k] + ln_b[k];
}

extern "C" void kernel_launch(void* const* d_in, const int* in_sizes, int n_in,
                              void* d_out, int out_size, void* d_ws, size_t ws_size,
                              hipStream_t stream) {
    const float* x      = (const float*)d_in[0];
    const float* fc1_w  = (const float*)d_in[1];
    const float* fc1_b  = (const float*)d_in[2];
    const float* fc2_w  = (const float*)d_in[3];
    const float* fc2_b  = (const float*)d_in[4];
    const float* glu_w  = (const float*)d_in[5];
    const float* glu_b  = (const float*)d_in[6];
    const float* skip_w = (const float*)d_in[7];
    const float* skip_b = (const float*)d_in[8];
    const float* ln_g   = (const float*)d_in[9];
    const float* ln_b   = (const float*)d_in[10];
    float* out = (float*)d_out;

    size_t need = (size_t)V_DIM * IMG_PER_V;  // 31,334,400 B
    if (ws_size >= need) {
        unsigned short* ws = (unsigned short*)d_ws;
        prep_weights<<<V_DIM * 4, 256, 0, stream>>>(fc2_w, glu_w, ws);
        grn_main<<<V_DIM * (N_TOK / BM), 256, 0, stream>>>(
            x, fc1_w, fc1_b, fc2_b, glu_b, skip_w, skip_b, ln_g, ln_b, ws, out);
    } else {
        grn_fallback<<<N_TOK * V_DIM, 160, 0, stream>>>(
            x, fc1_w, fc1_b, fc2_w, fc2_b, glu_w, glu_b, skip_w, skip_b, ln_g, ln_b, out);
    }
}

// Round 7
// 541.540 us; speedup vs baseline: 1.0281x; 1.0008x over previous
//
#include <hip/hip_runtime.h>

#define N_TOK 2048
#define V_DIM 204
#define H_DIM 160
#define G_DIM 320
#define BM 64
#define LN_EPSF 1e-5f

typedef short s8v __attribute__((ext_vector_type(8)));
typedef unsigned short u16x8 __attribute__((ext_vector_type(8)));
typedef float f32x4 __attribute__((ext_vector_type(4)));

// per-v bf16 weight image, K-major: [W1T][GLU half0][GLU half1]
// each sub-image: [chunk=k/8][row=out_col][8 bf16] = 20*160*16 B
#define IMG_SUB 51200
#define IMG_PER_V (3 * IMG_SUB)

__device__ __forceinline__ unsigned short f2bf(float f) {
    union { float f; unsigned int u; } a;
    a.f = f;
    unsigned int r = a.u + 0x7fffu + ((a.u >> 16) & 1u);  // RNE (prep keeps exact RNE)
    return (unsigned short)(r >> 16);
}

__device__ __forceinline__ unsigned short f2bf_fast(float f) {
    union { float f; unsigned int u; } a;
    a.f = f;
    return (unsigned short)((a.u + 0x8000u) >> 16);  // round-half-up: 2 instrs
}

// prep: 4 blocks per v. p=0,1: fc2 transpose (kout half p). p=2,3: glu half (p-2).
__global__ __launch_bounds__(256) void prep_weights(const float* __restrict__ fc2_w,
                                                    const float* __restrict__ glu_w,
                                                    unsigned short* __restrict__ ws) {
    int b = blockIdx.x;
    int v = b >> 2, p = b & 3;
    int t = threadIdx.x;
    char* img = (char*)ws + (size_t)v * IMG_PER_V;
    if (p < 2) {
        // fc2_w transpose for kout in [p*80, p*80+80)
        __shared__ float tile[H_DIM][81];
        const float* w1 = fc2_w + (size_t)v * H_DIM * H_DIM + p * 80;
        for (int i = t; i < H_DIM * 80; i += 256) {
            int r = i / 80, c = i % 80;
            tile[r][c] = w1[(size_t)r * H_DIM + c];
        }
        __syncthreads();
        for (int c2 = t; c2 < 20 * 80; c2 += 256) {
            int chunk = c2 / 80, ko = c2 % 80;
            u16x8 pk;
            #pragma unroll
            for (int j = 0; j < 8; j++) pk[j] = f2bf(tile[chunk * 8 + j][ko]);
            *(u16x8*)(img + (size_t)(chunk * 160 + p * 80 + ko) * 16) = pk;
        }
    } else {
        // glu half: rows [half*160, +160) of glu_w; no transpose, granule repack
        int half = p - 2;
        const float* w2 = glu_w + (size_t)v * G_DIM * H_DIM + (size_t)half * H_DIM * H_DIM;
        char* dst = img + IMG_SUB + (size_t)half * IMG_SUB;
        for (int c = t; c < 3200; c += 256) {
            int grow = c / 20, chunk = c % 20;   // read-coalesced order
            const float* src = w2 + (size_t)grow * H_DIM + chunk * 8;
            f32x4 lo = *(const f32x4*)src;
            f32x4 hi = *(const f32x4*)(src + 4);
            u16x8 pk;
            #pragma unroll
            for (int j = 0; j < 4; j++) { pk[j] = f2bf(lo[j]); pk[4 + j] = f2bf(hi[j]); }
            *(u16x8*)(dst + (size_t)(chunk * 160 + grow) * 16) = pk;
        }
    }
}

__global__ __launch_bounds__(256, 3) void grn_main(
    const float* __restrict__ x,
    const float* __restrict__ fc1_w, const float* __restrict__ fc1_b,
    const float* __restrict__ fc2_b, const float* __restrict__ glu_b,
    const float* __restrict__ skip_w, const float* __restrict__ skip_b,
    const float* __restrict__ ln_g, const float* __restrict__ ln_b,
    const unsigned short* __restrict__ ws, float* __restrict__ out)
{
    // K-major LDS: [chunk][row][16B]; holds h then c1 (overlay). B comes from L2.
    __shared__ __align__(16) unsigned short hc_lds[20 * 64 * 8];  // 20480 B
    __shared__ __align__(16) float2 red_lds[BM * 2];              // 1024 B (LN scratch)

    int bid = blockIdx.x;
    // XCD-bijective swizzle: 6528 blocks = 8 XCDs * 816; 32 tiles of a v adjacent on one XCD
    int swb = (bid & 7) * 816 + (bid >> 3);
    int v  = swb >> 5;
    int n0 = (swb & 31) * BM;

    int t = threadIdx.x;
    int lane = t & 63;
    int wv = t >> 6;
    int wr = wv >> 1;      // rows wr*32..+32
    int wc = wv & 1;       // cols wc*80..+80
    int col = lane & 15;
    int kg  = lane >> 4;

    const char* img = (const char*)ws + (size_t)v * IMG_PER_V;
    // per-lane B base within a sub-image: lane picks (kg, col); kk/n offsets are immediates
    const char* bbase = img + kg * 2560 + (wc * 80 + col) * 16;

    // ---- produce h = elu(x*fc1_w + fc1_b), K-major bf16, into LDS ----
    const float* fw = fc1_w + v * H_DIM;
    const float* fb = fc1_b + v * H_DIM;
    for (int i = t; i < 20 * BM; i += 256) {
        int chunk = i >> 6, row = i & 63;
        float xv = x[(size_t)(n0 + row) * V_DIM + v];
        int k0 = chunk * 8;
        u16x8 pk;
        #pragma unroll
        for (int j = 0; j < 8; j++) {
            float z = xv * fw[k0 + j] + fb[k0 + j];
            float e = z > 0.f ? z : (__expf(z) - 1.f);
            pk[j] = f2bf_fast(e);
        }
        *(u16x8*)((char*)hc_lds + chunk * 1024 + row * 16) = pk;
    }
    __syncthreads();  // bar1: h visible

    int arow = wr * 32 + col;

    // ---- GEMM1: c1 = h @ fc2_w (A from LDS, B from L2-resident image) ----
    s8v a1[2][5];
    #pragma unroll
    for (int m = 0; m < 2; m++)
        #pragma unroll
        for (int kk = 0; kk < 5; kk++)
            a1[m][kk] = *(const s8v*)((const char*)hc_lds +
                         (kk * 4 + kg) * 1024 + (arow + m * 16) * 16);

    f32x4 acc[2][5];
    #pragma unroll
    for (int m = 0; m < 2; m++)
        #pragma unroll
        for (int n = 0; n < 5; n++) acc[m][n] = (f32x4){0.f, 0.f, 0.f, 0.f};

    #pragma unroll
    for (int kk = 0; kk < 5; kk++) {
        s8v b[5];
        #pragma unroll
        for (int n = 0; n < 5; n++)
            b[n] = *(const s8v*)(bbase + kk * 10240 + n * 256);
        #pragma unroll
        for (int n = 0; n < 5; n++)
            #pragma unroll
            for (int m = 0; m < 2; m++)
                acc[m][n] = __builtin_amdgcn_mfma_f32_16x16x32_bf16(a1[m][kk], b[n], acc[m][n], 0, 0, 0);
    }
    __syncthreads();  // bar2: all h reads done, hc reusable

    // ---- epilogue1: + fc2_b, bf16, c1 into hc ----
    const float* f2b = fc2_b + v * H_DIM;
    #pragma unroll
    for (int n = 0; n < 5; n++) {
        int gc = wc * 80 + n * 16 + col;
        float bias = f2b[gc];
        int cbase = (gc >> 3) * 1024 + (gc & 7) * 2;
        #pragma unroll
        for (int m = 0; m < 2; m++)
            #pragma unroll
            for (int j = 0; j < 4; j++) {
                int row = wr * 32 + m * 16 + kg * 4 + j;
                *(unsigned short*)((char*)hc_lds + cbase + row * 16) = f2bf_fast(acc[m][n][j] + bias);
            }
    }
    __syncthreads();  // bar3: c1 visible

    // ---- GEMM2a/2b: fc_out and gate (A from LDS, B from L2-resident image) ----
    s8v a2[2][5];
    #pragma unroll
    for (int m = 0; m < 2; m++)
        #pragma unroll
        for (int kk = 0; kk < 5; kk++)
            a2[m][kk] = *(const s8v*)((const char*)hc_lds +
                         (kk * 4 + kg) * 1024 + (arow + m * 16) * 16);

    f32x4 af[2][5];
    #pragma unroll
    for (int m = 0; m < 2; m++)
        #pragma unroll
        for (int n = 0; n < 5; n++) af[m][n] = (f32x4){0.f, 0.f, 0.f, 0.f};

    #pragma unroll
    for (int kk = 0; kk < 5; kk++) {
        s8v b[5];
        #pragma unroll
        for (int n = 0; n < 5; n++)
            b[n] = *(const s8v*)(bbase + IMG_SUB + kk * 10240 + n * 256);
        #pragma unroll
        for (int n = 0; n < 5; n++)
            #pragma unroll
            for (int m = 0; m < 2; m++)
                af[m][n] = __builtin_amdgcn_mfma_f32_16x16x32_bf16(a2[m][kk], b[n], af[m][n], 0, 0, 0);
    }

    f32x4 ag[2][5];
    #pragma unroll
    for (int m = 0; m < 2; m++)
        #pragma unroll
        for (int n = 0; n < 5; n++) ag[m][n] = (f32x4){0.f, 0.f, 0.f, 0.f};

    #pragma unroll
    for (int kk = 0; kk < 5; kk++) {
        s8v b[5];
        #pragma unroll
        for (int n = 0; n < 5; n++)
            b[n] = *(const s8v*)(bbase + 2 * IMG_SUB + kk * 10240 + n * 256);
        #pragma unroll
        for (int n = 0; n < 5; n++)
            #pragma unroll
            for (int m = 0; m < 2; m++)
                ag[m][n] = __builtin_amdgcn_mfma_f32_16x16x32_bf16(a2[m][kk], b[n], ag[m][n], 0, 0, 0);
    }

    // ---- epilogue2: GLU + skip + LayerNorm + store ----
    const float* gb  = glu_b + v * G_DIM;
    const float* sw_ = skip_w + v * H_DIM;
    const float* sb_ = skip_b + v * H_DIM;
    float bfo[5], bga[5], sww[5], sbb[5], lng[5], lnb[5];
    #pragma unroll
    for (int n = 0; n < 5; n++) {
        int gc = wc * 80 + n * 16 + col;
        bfo[n] = gb[gc]; bga[n] = gb[H_DIM + gc];
        sww[n] = sw_[gc]; sbb[n] = sb_[gc];
        lng[n] = ln_g[gc]; lnb[n] = ln_b[gc];
    }
    float xrow[2][4];
    #pragma unroll
    for (int m = 0; m < 2; m++)
        #pragma unroll
        for (int j = 0; j < 4; j++)
            xrow[m][j] = x[(size_t)(n0 + wr * 32 + m * 16 + kg * 4 + j) * V_DIM + v];

    float y[2][5][4];
    float sum[2][4] = {}, ssq[2][4] = {};
    #pragma unroll
    for (int n = 0; n < 5; n++) {
        #pragma unroll
        for (int m = 0; m < 2; m++)
            #pragma unroll
            for (int j = 0; j < 4; j++) {
                float fo = af[m][n][j] + bfo[n];
                float ga = ag[m][n][j] + bga[n];
                float hh = fo / (1.f + __expf(-ga));
                float yv = xrow[m][j] * sww[n] + sbb[n] + hh;
                y[m][n][j] = yv;
                sum[m][j] += yv;
                ssq[m][j] += yv * yv;
            }
    }
    #pragma unroll
    for (int msk = 1; msk < 16; msk <<= 1)
        #pragma unroll
        for (int m = 0; m < 2; m++)
            #pragma unroll
            for (int j = 0; j < 4; j++) {
                sum[m][j] += __shfl_xor(sum[m][j], msk, 64);
                ssq[m][j] += __shfl_xor(ssq[m][j], msk, 64);
            }

    // cross-wave (wc pair) reduction through the dedicated scratch array
    if (col == 0) {
        #pragma unroll
        for (int m = 0; m < 2; m++)
            #pragma unroll
            for (int j = 0; j < 4; j++) {
                int row = wr * 32 + m * 16 + kg * 4 + j;
                red_lds[row * 2 + wc] = make_float2(sum[m][j], ssq[m][j]);
            }
    }
    __syncthreads();  // bar4: partner sums visible

    float mu_[2][4], rs_[2][4];
    #pragma unroll
    for (int m = 0; m < 2; m++)
        #pragma unroll
        for (int j = 0; j < 4; j++) {
            int row = wr * 32 + m * 16 + kg * 4 + j;
            f32x4 p = *(const f32x4*)&red_lds[row * 2];
            float mu = (p[0] + p[2]) * (1.f / H_DIM);
            float var = (p[1] + p[3]) * (1.f / H_DIM) - mu * mu;
            mu_[m][j] = mu;
            rs_[m][j] = rsqrtf(var + LN_EPSF);
        }

    #pragma unroll
    for (int n = 0; n < 5; n++) {
        int gc = wc * 80 + n * 16 + col;
        #pragma unroll
        for (int m = 0; m < 2; m++)
            #pragma unroll
            for (int j = 0; j < 4; j++) {
                int row = n0 + wr * 32 + m * 16 + kg * 4 + j;
                out[((size_t)row * V_DIM + v) * H_DIM + gc] =
                    (y[m][n][j] - mu_[m][j]) * rs_[m][j] * lng[n] + lnb[n];
            }
    }
}

// correctness fallback if ws is too small for the bf16 weight images
__global__ __launch_bounds__(160) void grn_fallback(
    const float* __restrict__ x,
    const float* __restrict__ fc1_w, const float* __restrict__ fc1_b,
    const float* __restrict__ fc2_w, const float* __restrict__ fc2_b,
    const float* __restrict__ glu_w, const float* __restrict__ glu_b,
    const float* __restrict__ skip_w, const float* __restrict__ skip_b,
    const float* __restrict__ ln_g, const float* __restrict__ ln_b,
    float* __restrict__ out)
{
    int n = blockIdx.x / V_DIM, v = blockIdx.x % V_DIM;
    int k = threadIdx.x;
    __shared__ float hb[H_DIM], c1[H_DIM], yb[H_DIM];
    float xv = x[(size_t)n * V_DIM + v];
    float z = xv * fc1_w[v * H_DIM + k] + fc1_b[v * H_DIM + k];
    hb[k] = z > 0.f ? z : (__expf(z) - 1.f);
    __syncthreads();
    const float* w1 = fc2_w + (size_t)v * H_DIM * H_DIM;
    float s = fc2_b[v * H_DIM + k];
    for (int i = 0; i < H_DIM; i++) s += hb[i] * w1[(size_t)i * H_DIM + k];
    c1[k] = s;
    __syncthreads();
    const float* w2 = glu_w + (size_t)v * G_DIM * H_DIM;
    float sf = glu_b[v * G_DIM + k], sg = glu_b[v * G_DIM + H_DIM + k];
    for (int i = 0; i < H_DIM; i++) {
        float cv = c1[i];
        sf += cv * w2[(size_t)k * H_DIM + i];
        sg += cv * w2[(size_t)(k + H_DIM) * H_DIM + i];
    }
    float y = xv * skip_w[v * H_DIM + k] + skip_b[v * H_DIM + k] + sf / (1.f + __expf(-sg));
    yb[k] = y;
    __syncthreads();
    float sum = 0.f, ssq = 0.f;
    for (int i = 0; i < H_DIM; i++) { sum += yb[i]; ssq += yb[i] * yb[i]; }
    float mu = sum / H_DIM;
    float var = ssq / H_DIM - mu * mu;
    out[((size_t)n * V_DIM + v) * H_DIM + k] =
        (y - mu) * rsqrtf(var + LN_EPSF) * ln_g[k] + ln_b[k];
}

extern "C" void kernel_launch(void* const* d_in, const int* in_sizes, int n_in,
                              void* d_out, int out_size, void* d_ws, size_t ws_size,
                              hipStream_t stream) {
    const float* x      = (const float*)d_in[0];
    const float* fc1_w  = (const float*)d_in[1];
    const float* fc1_b  = (const float*)d_in[2];
    const float* fc2_w  = (const float*)d_in[3];
    const float* fc2_b  = (const float*)d_in[4];
    const float* glu_w  = (const float*)d_in[5];
    const float* glu_b  = (const float*)d_in[6];
    const float* skip_w = (const float*)d_in[7];
    const float* skip_b = (const float*)d_in[8];
    const float* ln_g   = (const float*)d_in[9];
    const float* ln_b   = (const float*)d_in[10];
    float* out = (float*)d_out;

    size_t need = (size_t)V_DIM * IMG_PER_V;  // 31,334,400 B
    if (ws_size >= need) {
        unsigned short* ws = (unsigned short*)d_ws;
        prep_weights<<<V_DIM * 4, 256, 0, stream>>>(fc2_w, glu_w, ws);
        grn_main<<<V_DIM * (N_TOK / BM), 256, 0, stream>>>(
            x, fc1_w, fc1_b, fc2_b, glu_b, skip_w, skip_b, ln_g, ln_b, ws, out);
    } else {
        grn_fallback<<<N_TOK * V_DIM, 160, 0, stream>>>(
            x, fc1_w, fc1_b, fc2_w, fc2_b, glu_w, glu_b, skip_w, skip_b, ln_g, ln_b, out);
    }
}